// Round 18
// baseline (320.107 us; speedup 1.0000x reference)
//
#include <hip/hip_runtime.h>
#include <hip/hip_cooperative_groups.h>

namespace cg = cooperative_groups;

// GCNe: 3-layer edge-weighted GCN + mean pool + linear head.
// N=100000, E=1000000, F=H=64, G=256, C=10.
//
// R18: layers+pool fused into ONE cooperative kernel (grid 256x512 = 1
// block/CU, grid.sync between layers) -- layers are at the fabric random-read
// BW wall (~2.4 TB/s on compulsory 12.8MB x 8 XCD traffic), so we harvest
// launch-gap overhead instead. 4 dispatches: cvtz, scatterC, sortCB, mega.

#define GCN_F 64
#define GCN_C 10
#define CB_SHIFT 9
#define CB_NODES 512          // nodes per coarse bucket
#define NCB_MAX 200           // >= ceil(N/512)=196
#define CAP 7168              // bucket slice stride (mean 5102, +29 sigma)
#define SC_CHUNK 2048         // edges per scatter block

typedef __attribute__((ext_vector_type(8))) short bf16x8;
typedef __attribute__((ext_vector_type(4))) float f32x4;

__device__ __forceinline__ unsigned short f2b(float v) {
    union { float f; unsigned int u; } c; c.f = v;
    unsigned int u = c.u;
    return (unsigned short)((u + 0x7FFFu + ((u >> 16) & 1u)) >> 16);  // RNE
}
__device__ __forceinline__ float b2f(unsigned short u) {
    union { unsigned int u; float f; } c; c.u = ((unsigned int)u) << 16; return c.f;
}

// --------------------- fp32 -> bf16 convert + zero cursors
__global__ __launch_bounds__(256) void cvtz_kernel(const float* __restrict__ in,
                                                   unsigned short* __restrict__ out,
                                                   int n4, int* __restrict__ zp, int zn) {
    int gid = blockIdx.x * 256 + threadIdx.x;
    if (gid < zn) zp[gid] = 0;
    int stride = gridDim.x * 256;
    for (int i = gid; i < n4; i += stride) {
        float4 v = reinterpret_cast<const float4*>(in)[i];
        ushort4 o;
        o.x = f2b(v.x); o.y = f2b(v.y); o.z = f2b(v.z); o.w = f2b(v.w);
        reinterpret_cast<ushort4*>(out)[i] = o;
    }
}

// ------------- scatter: block-local counting sort + chunk-reserved run writes
// into fixed-stride bucket slices [bk*CAP, ...). rec.x = src | (dst&511)<<17.
__global__ __launch_bounds__(256) void scatterC_kernel(
    const int* __restrict__ src, const int* __restrict__ dst,
    const float* __restrict__ ew,
    int* __restrict__ gcursor, int2* __restrict__ ebufA, int E, int NCB) {
    __shared__ int2 recS[SC_CHUNK];     // 16 KB
    __shared__ int gdest[SC_CHUNK];     // 8 KB
    __shared__ int hist[NCB_MAX];
    __shared__ int lstart[NCB_MAX];
    __shared__ int gbase[NCB_MAX];
    __shared__ int cur[NCB_MAX];
    __shared__ int sb[256];

    int tid = threadIdx.x;
    int base = blockIdx.x * SC_CHUNK;
    int m = min(SC_CHUNK, E - base);

    for (int i = tid; i < NCB; i += 256) hist[i] = 0;
    __syncthreads();

    int2 rec[8];
    int bk[8];
#pragma unroll
    for (int k = 0; k < 8; ++k) {
        int e = base + k * 256 + tid;
        if (e < E) {
            int d = dst[e];
            bk[k] = d >> CB_SHIFT;
            rec[k] = make_int2(src[e] | ((d & (CB_NODES - 1)) << 17),
                               __float_as_int(ew[e]));
            atomicAdd(&hist[bk[k]], 1);
        } else bk[k] = -1;
    }
    __syncthreads();

    // block-wide exclusive scan of hist[0..NCB)
    int v = (tid < NCB) ? hist[tid] : 0;
    sb[tid] = v;
    __syncthreads();
    for (int o = 1; o < 256; o <<= 1) {
        int t = (tid >= o) ? sb[tid - o] : 0;
        __syncthreads();
        sb[tid] += t;
        __syncthreads();
    }
    if (tid < NCB) {
        int excl = sb[tid] - v;
        lstart[tid] = excl;
        cur[tid] = excl;
        gbase[tid] = (v > 0) ? atomicAdd(&gcursor[tid], v) : 0;  // reserve run
    }
    __syncthreads();

    // place records into LDS sorted by bucket; record global destination
#pragma unroll
    for (int k = 0; k < 8; ++k) {
        if (bk[k] >= 0) {
            int p = atomicAdd(&cur[bk[k]], 1);
            recS[p] = rec[k];
            gdest[p] = bk[k] * CAP + gbase[bk[k]] + (p - lstart[bk[k]]);
        }
    }
    __syncthreads();

    // coalesced staged write (consecutive i within a run -> consecutive dest)
    for (int i = tid; i < m; i += 256) ebufA[gdest[i]] = recS[i];
}

// -------------- per-bucket LDS counting sort -> sorted edges + node offsets
// Also records bend[cb] = slice-local end, for bucket-boundary nodes.
__global__ __launch_bounds__(256) void sortCB_kernel(
    const int2* __restrict__ ebufA, const int* __restrict__ gcursor,
    int2* __restrict__ ebufS, int* __restrict__ offsets, int* __restrict__ bend,
    int N, int E) {
    __shared__ int2 rec[CAP];                 // 56 KB
    __shared__ int cnt[CB_NODES];
    __shared__ int cur[CB_NODES];
    __shared__ int sbuf[256];
    int cb = blockIdx.x, tid = threadIdx.x;
    int e0 = cb * CAP;
    int m = min(gcursor[cb], CAP);
    if (tid == 0) bend[cb] = e0 + m;

    for (int i = tid; i < m; i += 256) rec[i] = ebufA[e0 + i];
    for (int i = tid; i < CB_NODES; i += 256) cnt[i] = 0;
    __syncthreads();
    for (int i = tid; i < m; i += 256)
        atomicAdd(&cnt[(unsigned)rec[i].x >> 17], 1);
    __syncthreads();

    // exclusive scan over 512 counts (thread owns 2)
    int c0 = cnt[2 * tid], c1 = cnt[2 * tid + 1];
    int part = c0 + c1;
    sbuf[tid] = part;
    __syncthreads();
    for (int off = 1; off < 256; off <<= 1) {
        int t = (tid >= off) ? sbuf[tid - off] : 0;
        __syncthreads();
        sbuf[tid] += t;
        __syncthreads();
    }
    int excl = sbuf[tid] - part;
    int pre0 = excl, pre1 = excl + c0;
    cur[2 * tid] = pre0;
    cur[2 * tid + 1] = pre1;
    int g0 = cb * CB_NODES + 2 * tid;
    if (g0 <= N)     offsets[g0]     = e0 + pre0;
    if (g0 + 1 <= N) offsets[g0 + 1] = e0 + pre1;
    __syncthreads();

    for (int i = tid; i < m; i += 256) {
        int d9 = (unsigned)rec[i].x >> 17;
        int pos = atomicAdd(&cur[d9], 1);
        ebufS[e0 + pos] = make_int2(rec[i].x & 0x1FFFF, rec[i].y);
    }
}

// ---------------- cooperative mega-kernel: 3 fused layers + mean-pool + head
// grid 256 x 512thr (1 block/CU). Per layer: wave-strided 16-node groups,
// spmm (2x 8-node halves, int4 gathers, ds_bpermute broadcast) -> padded LDS
// rows -> wave-local MFMA tile. grid.sync() between layers.
__global__ __launch_bounds__(512) void mega_kernel(
    unsigned short* __restrict__ buf0, unsigned short* __restrict__ buf1,
    const int* __restrict__ offsets, const int* __restrict__ bend,
    const int2* __restrict__ ebufS,
    const float* __restrict__ W1r, const float* __restrict__ W1s, const float* __restrict__ b1,
    const float* __restrict__ W2r, const float* __restrict__ W2s, const float* __restrict__ b2,
    const float* __restrict__ W3r, const float* __restrict__ W3s, const float* __restrict__ b3,
    const float* __restrict__ Wl, const float* __restrict__ bl,
    const int* __restrict__ batch, float* __restrict__ out,
    int ngroups, int n)
{
    cg::grid_group grid = cg::this_grid();
    __shared__ __align__(16) unsigned short bfrag[2][2][4][64][8];  // 16 KB
    __shared__ __align__(16) unsigned short aggS[8][16][72];        // 18.4 KB
    __shared__ float sp[8][GCN_F];                                  // 2 KB

    int tid = threadIdx.x, lane = tid & 63, wave = tid >> 6;
    int l8 = lane & 7;
    int grp = lane >> 3;
    int gbase = (lane & 56) << 2;           // byte addr of group's lane 0
    int l15 = lane & 15, lhi = lane >> 4;

    for (int layer = 0; layer < 3; ++layer) {
        if (layer) grid.sync();
        const unsigned short* xin = (layer & 1) ? buf1 : buf0;
        unsigned short* outb      = (layer & 1) ? buf0 : buf1;
        const float* Wr = (layer == 0) ? W1r : (layer == 1) ? W2r : W3r;
        const float* Ws = (layer == 0) ? W1s : (layer == 1) ? W2s : W3s;
        const float* b  = (layer == 0) ? b1  : (layer == 1) ? b2  : b3;

        // build B fragments: [op][ks][ct][lane][j]
        for (int i = tid; i < 8192; i += 512) {
            int op = i >> 12;
            int ks = (i >> 11) & 1;
            int ct = (i >> 9) & 3;
            int l  = (i >> 3) & 63;
            int j  = i & 7;
            int k   = ks * 32 + (l >> 4) * 8 + j;
            int col = ct * 16 + (l & 15);
            const float* W = op ? Ws : Wr;
            ((unsigned short*)bfrag)[i] = f2b(W[k * GCN_F + col]);
        }
        __syncthreads();

        bf16x8 B[2][2][4];
#pragma unroll
        for (int op = 0; op < 2; ++op)
#pragma unroll
            for (int ks = 0; ks < 2; ++ks)
#pragma unroll
                for (int ct = 0; ct < 4; ++ct)
                    B[op][ks][ct] = *reinterpret_cast<const bf16x8*>(&bfrag[op][ks][ct][lane][0]);

        float bias[4];
#pragma unroll
        for (int ct = 0; ct < 4; ++ct) bias[ct] = b[ct * 16 + l15];

        int wid = blockIdx.x * 8 + wave;
        int nw  = gridDim.x * 8;
        for (int gsel = wid; gsel < ngroups; gsel += nw) {
            int wbase = gsel * 16;

            // ---- spmm phase: this group's 16 nodes, two 8-node halves
#pragma unroll
            for (int half = 0; half < 2; ++half) {
                int node = wbase + half * 8 + grp;
                bool nv = node < n;
                int p0 = 0, p1 = 0;
                if (nv) {
                    p0 = offsets[node];
                    // bucket's last node ends at the slice end, not the next
                    // bucket's slice start (the gap is uninitialized!)
                    p1 = ((node & (CB_NODES - 1)) == CB_NODES - 1)
                             ? bend[node >> CB_SHIFT] : offsets[node + 1];
                }
                float acc[8] = {0.f, 0.f, 0.f, 0.f, 0.f, 0.f, 0.f, 0.f};

                int idx = p0 + l8;
                bool v = idx < p1;
                if (__any(v)) {
                    int2 er = ebufS[v ? idx : 0];
                    int s  = v ? er.x : 0;
                    int wb = v ? er.y : 0;

                    for (int c = 1;; ++c) {
                        int idxn = p0 + c * 8 + l8;
                        bool vn = idxn < p1;
                        int2 ern = ebufS[vn ? idxn : 0];

                        int sj[8], wj[8];
#pragma unroll
                        for (int j = 0; j < 8; ++j) {
                            sj[j] = __builtin_amdgcn_ds_bpermute(gbase + (j << 2), s);
                            wj[j] = __builtin_amdgcn_ds_bpermute(gbase + (j << 2), wb);
                        }
                        int4 r[8];
#pragma unroll
                        for (int j = 0; j < 8; ++j)
                            r[j] = *reinterpret_cast<const int4*>(
                                xin + ((size_t)sj[j] << 6) + l8 * 8);
#pragma unroll
                        for (int j = 0; j < 8; ++j) {
                            float wf = __int_as_float(wj[j]);
                            acc[0] = fmaf(__int_as_float(r[j].x << 16),        wf, acc[0]);
                            acc[1] = fmaf(__int_as_float(r[j].x & 0xFFFF0000), wf, acc[1]);
                            acc[2] = fmaf(__int_as_float(r[j].y << 16),        wf, acc[2]);
                            acc[3] = fmaf(__int_as_float(r[j].y & 0xFFFF0000), wf, acc[3]);
                            acc[4] = fmaf(__int_as_float(r[j].z << 16),        wf, acc[4]);
                            acc[5] = fmaf(__int_as_float(r[j].z & 0xFFFF0000), wf, acc[5]);
                            acc[6] = fmaf(__int_as_float(r[j].w << 16),        wf, acc[6]);
                            acc[7] = fmaf(__int_as_float(r[j].w & 0xFFFF0000), wf, acc[7]);
                        }

                        if (!__any(vn)) break;
                        s  = vn ? ern.x : 0;
                        wb = vn ? ern.y : 0;
                    }
                }

                int4 o;
                o.x = (int)f2b(acc[0]) | ((int)f2b(acc[1]) << 16);
                o.y = (int)f2b(acc[2]) | ((int)f2b(acc[3]) << 16);
                o.z = (int)f2b(acc[4]) | ((int)f2b(acc[5]) << 16);
                o.w = (int)f2b(acc[6]) | ((int)f2b(acc[7]) << 16);
                *reinterpret_cast<int4*>(&aggS[wave][half * 8 + grp][l8 * 8]) = o;
            }
            // rows are wave-local: no block barrier needed.

            // ---- GEMM phase: 16-row MFMA tile for this group's nodes
            bf16x8 a0 = *reinterpret_cast<const bf16x8*>(&aggS[wave][l15][lhi * 8]);
            bf16x8 a1 = *reinterpret_cast<const bf16x8*>(&aggS[wave][l15][32 + lhi * 8]);
            const unsigned short* xp = xin + (size_t)min(wbase + l15, n - 1) * GCN_F + lhi * 8;
            bf16x8 x0 = *reinterpret_cast<const bf16x8*>(xp);
            bf16x8 x1 = *reinterpret_cast<const bf16x8*>(xp + 32);

#pragma unroll
            for (int ct = 0; ct < 4; ++ct) {
                f32x4 acc = {0.f, 0.f, 0.f, 0.f};
                acc = __builtin_amdgcn_mfma_f32_16x16x32_bf16(a0, B[0][0][ct], acc, 0, 0, 0);
                acc = __builtin_amdgcn_mfma_f32_16x16x32_bf16(a1, B[0][1][ct], acc, 0, 0, 0);
                acc = __builtin_amdgcn_mfma_f32_16x16x32_bf16(x0, B[1][0][ct], acc, 0, 0, 0);
                acc = __builtin_amdgcn_mfma_f32_16x16x32_bf16(x1, B[1][1][ct], acc, 0, 0, 0);
                int col = ct * 16 + l15;
#pragma unroll
                for (int r = 0; r < 4; ++r) {
                    int orow = wbase + lhi * 4 + r;
                    if (orow < n) {
                        float v = fmaxf(acc[r] + bias[ct], 0.f);
                        outb[(size_t)orow * GCN_F + col] = f2b(v);
                    }
                }
            }
        }
        __syncthreads();   // bfrag reuse next layer
    }

    grid.sync();

    // ---- pool + head phase: block g handles graph g (gridDim == G)
    {
        const unsigned short* h = buf1;   // layer 3 output
        int g = blockIdx.x;
        int i0, i1;
        {
            int lo = 0, hi = n;
            while (lo < hi) { int mid = (lo + hi) >> 1; if (batch[mid] < g) lo = mid + 1; else hi = mid; }
            i0 = lo;
            lo = i0; hi = n;
            while (lo < hi) { int mid = (lo + hi) >> 1; if (batch[mid] < g + 1) lo = mid + 1; else hi = mid; }
            i1 = lo;
        }

        float s = 0.f;
        for (int i = i0 + wave; i < i1; i += 8) s += b2f(h[(size_t)i * GCN_F + lane]);

        sp[wave][lane] = s;
        __syncthreads();
        if (wave == 0) {
            float tot = 0.f;
#pragma unroll
            for (int w = 0; w < 8; ++w) tot += sp[w][lane];
            float cntf = (float)(i1 - i0);
            sp[0][lane] = tot / fmaxf(cntf, 1.f);
        }
        __syncthreads();
        if (tid < GCN_C) {
            float o = bl[tid];
#pragma unroll
            for (int j = 0; j < GCN_F; ++j) o += sp[0][j] * Wl[j * GCN_C + tid];
            out[g * GCN_C + tid] = o;
        }
    }
}

// --------------------------------------------------------------------------
extern "C" void kernel_launch(void* const* d_in, const int* in_sizes, int n_in,
                              void* d_out, int out_size, void* d_ws, size_t ws_size,
                              hipStream_t stream) {
    const float* x     = (const float*)d_in[0];
    const int*   ei    = (const int*)d_in[1];
    const float* ew    = (const float*)d_in[2];
    const int*   batch = (const int*)d_in[3];
    const float* W1r   = (const float*)d_in[4];
    const float* W1s   = (const float*)d_in[5];
    const float* b1    = (const float*)d_in[6];
    const float* W2r   = (const float*)d_in[7];
    const float* W2s   = (const float*)d_in[8];
    const float* b2    = (const float*)d_in[9];
    const float* W3r   = (const float*)d_in[10];
    const float* W3s   = (const float*)d_in[11];
    const float* b3    = (const float*)d_in[12];
    const float* Wl    = (const float*)d_in[13];
    const float* bl    = (const float*)d_in[14];
    float* out = (float*)d_out;

    const int N = in_sizes[0] / GCN_F;   // 100000
    const int E = in_sizes[2];           // 1000000
    const int G = out_size / GCN_C;      // 256
    const int NCB = (N + CB_NODES - 1) / CB_NODES;  // 196 coarse buckets
    int NGROUPS = (N + 15) / 16;         // 6250

    const int* src = ei;
    const int* dst = ei + E;

    // workspace layout (16B aligned)
    char* ws = (char*)d_ws;
    size_t off = 0;
    size_t csz = ((size_t)NCB * 4 + 15) & ~(size_t)15;
    int* gcursor = (int*)(ws + off);  off += csz;
    int* bend    = (int*)(ws + off);  off += csz;
    int* offsets = (int*)(ws + off);  off += ((size_t)(N + 1) * 4 + 15) & ~(size_t)15;
    int2* ebufA  = (int2*)(ws + off); off += (size_t)NCB * CAP * 8;   // 11.2 MB
    int2* ebufS  = (int2*)(ws + off); off += (size_t)NCB * CAP * 8;   // 11.2 MB
    unsigned short* buf0 = (unsigned short*)(ws + off); off += (size_t)N * GCN_F * 2;
    unsigned short* buf1 = (unsigned short*)(ws + off); off += (size_t)N * GCN_F * 2;

    int sblocks = (E + SC_CHUNK - 1) / SC_CHUNK;
    int zcount  = (int)(csz / 4);   // gcursor only
    int n = N;

    cvtz_kernel<<<1024, 256, 0, stream>>>(x, buf0, N * GCN_F / 4, gcursor, zcount);
    scatterC_kernel<<<sblocks, 256, 0, stream>>>(src, dst, ew, gcursor, ebufA, E, NCB);
    sortCB_kernel<<<NCB, 256, 0, stream>>>(ebufA, gcursor, ebufS, offsets, bend, N, E);

    void* args[] = {
        (void*)&buf0, (void*)&buf1, (void*)&offsets, (void*)&bend, (void*)&ebufS,
        (void*)&W1r, (void*)&W1s, (void*)&b1,
        (void*)&W2r, (void*)&W2s, (void*)&b2,
        (void*)&W3r, (void*)&W3s, (void*)&b3,
        (void*)&Wl, (void*)&bl, (void*)&batch, (void*)&out,
        (void*)&NGROUPS, (void*)&n
    };
    hipLaunchCooperativeKernel((const void*)mega_kernel, dim3(256), dim3(512),
                               args, 0, stream);
}

// Round 19
// 306.589 us; speedup vs baseline: 1.0441x; 1.0441x over previous
//
#include <hip/hip_runtime.h>

// GCNe: 3-layer edge-weighted GCN + mean pool + linear head.
// N=100000, E=1000000, F=H=64, G=256, C=10.
//
// R19 = R17 with 16-deep gather chunks (2 edge recs/lane, 16 int4 gathers in
// flight per wave = 16KB) to test whether the 46-50us layer plateau is fabric
// saturation (flat result) or per-wave in-flight shortage (speedup).
// launch_bounds(512,4) pins 4 waves/SIMD against the VGPR cliff.
// Edge order per node unchanged -> identical FP sum order -> same absmax.

#define GCN_F 64
#define GCN_C 10
#define CB_SHIFT 9
#define CB_NODES 512          // nodes per coarse bucket
#define NCB_MAX 200           // >= ceil(N/512)=196
#define CAP 7168              // bucket slice stride (mean 5102, +29 sigma)
#define SC_CHUNK 2048         // edges per scatter block

typedef __attribute__((ext_vector_type(8))) short bf16x8;
typedef __attribute__((ext_vector_type(4))) float f32x4;

__device__ __forceinline__ unsigned short f2b(float v) {
    union { float f; unsigned int u; } c; c.f = v;
    unsigned int u = c.u;
    return (unsigned short)((u + 0x7FFFu + ((u >> 16) & 1u)) >> 16);  // RNE
}
__device__ __forceinline__ float b2f(unsigned short u) {
    union { unsigned int u; float f; } c; c.u = ((unsigned int)u) << 16; return c.f;
}

// --------------------- fp32 -> bf16 convert + zero cursors
__global__ __launch_bounds__(256) void cvtz_kernel(const float* __restrict__ in,
                                                   unsigned short* __restrict__ out,
                                                   int n4, int* __restrict__ zp, int zn) {
    int gid = blockIdx.x * 256 + threadIdx.x;
    if (gid < zn) zp[gid] = 0;
    int stride = gridDim.x * 256;
    for (int i = gid; i < n4; i += stride) {
        float4 v = reinterpret_cast<const float4*>(in)[i];
        ushort4 o;
        o.x = f2b(v.x); o.y = f2b(v.y); o.z = f2b(v.z); o.w = f2b(v.w);
        reinterpret_cast<ushort4*>(out)[i] = o;
    }
}

// ------------- scatter: block-local counting sort + chunk-reserved run writes
// into fixed-stride bucket slices [bk*CAP, ...). rec.x = src | (dst&511)<<17.
__global__ __launch_bounds__(256) void scatterC_kernel(
    const int* __restrict__ src, const int* __restrict__ dst,
    const float* __restrict__ ew,
    int* __restrict__ gcursor, int2* __restrict__ ebufA, int E, int NCB) {
    __shared__ int2 recS[SC_CHUNK];     // 16 KB
    __shared__ int gdest[SC_CHUNK];     // 8 KB
    __shared__ int hist[NCB_MAX];
    __shared__ int lstart[NCB_MAX];
    __shared__ int gbase[NCB_MAX];
    __shared__ int cur[NCB_MAX];
    __shared__ int sb[256];

    int tid = threadIdx.x;
    int base = blockIdx.x * SC_CHUNK;
    int m = min(SC_CHUNK, E - base);

    for (int i = tid; i < NCB; i += 256) hist[i] = 0;
    __syncthreads();

    int2 rec[8];
    int bk[8];
#pragma unroll
    for (int k = 0; k < 8; ++k) {
        int e = base + k * 256 + tid;
        if (e < E) {
            int d = dst[e];
            bk[k] = d >> CB_SHIFT;
            rec[k] = make_int2(src[e] | ((d & (CB_NODES - 1)) << 17),
                               __float_as_int(ew[e]));
            atomicAdd(&hist[bk[k]], 1);
        } else bk[k] = -1;
    }
    __syncthreads();

    // block-wide exclusive scan of hist[0..NCB)
    int v = (tid < NCB) ? hist[tid] : 0;
    sb[tid] = v;
    __syncthreads();
    for (int o = 1; o < 256; o <<= 1) {
        int t = (tid >= o) ? sb[tid - o] : 0;
        __syncthreads();
        sb[tid] += t;
        __syncthreads();
    }
    if (tid < NCB) {
        int excl = sb[tid] - v;
        lstart[tid] = excl;
        cur[tid] = excl;
        gbase[tid] = (v > 0) ? atomicAdd(&gcursor[tid], v) : 0;  // reserve run
    }
    __syncthreads();

    // place records into LDS sorted by bucket; record global destination
#pragma unroll
    for (int k = 0; k < 8; ++k) {
        if (bk[k] >= 0) {
            int p = atomicAdd(&cur[bk[k]], 1);
            recS[p] = rec[k];
            gdest[p] = bk[k] * CAP + gbase[bk[k]] + (p - lstart[bk[k]]);
        }
    }
    __syncthreads();

    // coalesced staged write (consecutive i within a run -> consecutive dest)
    for (int i = tid; i < m; i += 256) ebufA[gdest[i]] = recS[i];
}

// -------------- per-bucket LDS counting sort -> sorted edges + node offsets
// Also records bend[cb] = slice-local end, for bucket-boundary nodes.
__global__ __launch_bounds__(256) void sortCB_kernel(
    const int2* __restrict__ ebufA, const int* __restrict__ gcursor,
    int2* __restrict__ ebufS, int* __restrict__ offsets, int* __restrict__ bend,
    int N, int E) {
    __shared__ int2 rec[CAP];                 // 56 KB
    __shared__ int cnt[CB_NODES];
    __shared__ int cur[CB_NODES];
    __shared__ int sbuf[256];
    int cb = blockIdx.x, tid = threadIdx.x;
    int e0 = cb * CAP;
    int m = min(gcursor[cb], CAP);
    if (tid == 0) bend[cb] = e0 + m;

    for (int i = tid; i < m; i += 256) rec[i] = ebufA[e0 + i];
    for (int i = tid; i < CB_NODES; i += 256) cnt[i] = 0;
    __syncthreads();
    for (int i = tid; i < m; i += 256)
        atomicAdd(&cnt[(unsigned)rec[i].x >> 17], 1);
    __syncthreads();

    // exclusive scan over 512 counts (thread owns 2)
    int c0 = cnt[2 * tid], c1 = cnt[2 * tid + 1];
    int part = c0 + c1;
    sbuf[tid] = part;
    __syncthreads();
    for (int off = 1; off < 256; off <<= 1) {
        int t = (tid >= off) ? sbuf[tid - off] : 0;
        __syncthreads();
        sbuf[tid] += t;
        __syncthreads();
    }
    int excl = sbuf[tid] - part;
    int pre0 = excl, pre1 = excl + c0;
    cur[2 * tid] = pre0;
    cur[2 * tid + 1] = pre1;
    int g0 = cb * CB_NODES + 2 * tid;
    if (g0 <= N)     offsets[g0]     = e0 + pre0;
    if (g0 + 1 <= N) offsets[g0 + 1] = e0 + pre1;
    __syncthreads();

    for (int i = tid; i < m; i += 256) {
        int d9 = (unsigned)rec[i].x >> 17;
        int pos = atomicAdd(&cur[d9], 1);
        ebufS[e0 + pos] = make_int2(rec[i].x & 0x1FFFF, rec[i].y);
    }
}

// ---------------- fused layer: 512-thr blocks, 8 waves; wave wid statically
// handles groups wid, wid+nw, ... Per group: spmm (2x 8-node halves, 16-deep
// int4 gather chunks, ds_bpermute broadcast) -> padded LDS rows -> wave-local
// MFMA tile: h = relu(agg@Wr + x@Ws + b).
__global__ __launch_bounds__(512, 4) void layer_kernel(
    const unsigned short* __restrict__ xin, const int* __restrict__ offsets,
    const int* __restrict__ bend, const int2* __restrict__ ebufS,
    const float* __restrict__ Wr, const float* __restrict__ Ws,
    const float* __restrict__ b, unsigned short* __restrict__ out,
    int ngroups, int n)
{
    __shared__ __align__(16) unsigned short bfrag[2][2][4][64][8];  // 16 KB
    __shared__ __align__(16) unsigned short aggS[8][16][72];        // 18.4 KB
    int tid = threadIdx.x, lane = tid & 63, wave = tid >> 6;

    // build B fragments: [op][ks][ct][lane][j]
    for (int i = tid; i < 8192; i += 512) {
        int op = i >> 12;
        int ks = (i >> 11) & 1;
        int ct = (i >> 9) & 3;
        int l  = (i >> 3) & 63;
        int j  = i & 7;
        int k   = ks * 32 + (l >> 4) * 8 + j;
        int col = ct * 16 + (l & 15);
        const float* W = op ? Ws : Wr;
        ((unsigned short*)bfrag)[i] = f2b(W[k * GCN_F + col]);
    }
    __syncthreads();

    int l8 = lane & 7;
    int grp = lane >> 3;
    int gbase = (lane & 56) << 2;           // byte addr of group's lane 0
    int l15 = lane & 15, lhi = lane >> 4;

    bf16x8 B[2][2][4];
#pragma unroll
    for (int op = 0; op < 2; ++op)
#pragma unroll
        for (int ks = 0; ks < 2; ++ks)
#pragma unroll
            for (int ct = 0; ct < 4; ++ct)
                B[op][ks][ct] = *reinterpret_cast<const bf16x8*>(&bfrag[op][ks][ct][lane][0]);

    float bias[4];
#pragma unroll
    for (int ct = 0; ct < 4; ++ct) bias[ct] = b[ct * 16 + l15];

    int wid = blockIdx.x * 8 + wave;
    int nw  = gridDim.x * 8;
    for (int gsel = wid; gsel < ngroups; gsel += nw) {
        int wbase = gsel * 16;

        // ---- spmm phase: this group's 16 nodes, two 8-node halves
#pragma unroll
        for (int half = 0; half < 2; ++half) {
            int node = wbase + half * 8 + grp;
            bool nv = node < n;
            int p0 = 0, p1 = 0;
            if (nv) {
                p0 = offsets[node];
                // bucket's last node ends at the slice end, not the next
                // bucket's slice start (the gap is uninitialized!)
                p1 = ((node & (CB_NODES - 1)) == CB_NODES - 1)
                         ? bend[node >> CB_SHIFT] : offsets[node + 1];
            }
            float acc[8] = {0.f, 0.f, 0.f, 0.f, 0.f, 0.f, 0.f, 0.f};

            // 16-deep chunks: lanes hold edges c*16+l8 and c*16+8+l8
            for (int c = 0; p0 + c * 16 < p1 || c == 0; ++c) {
                if (!__any(p0 + c * 16 + l8 < p1)) break;
                int idxA = p0 + c * 16 + l8;
                int idxB = idxA + 8;
                bool vA = idxA < p1;
                bool vB = idxB < p1;
                int2 erA = ebufS[vA ? idxA : 0];
                int2 erB = ebufS[vB ? idxB : 0];
                int sA = vA ? erA.x : 0, wbA = vA ? erA.y : 0;
                int sB = vB ? erB.x : 0, wbB = vB ? erB.y : 0;

                int sj[16], wj[16];
#pragma unroll
                for (int j = 0; j < 8; ++j) {
                    sj[j]     = __builtin_amdgcn_ds_bpermute(gbase + (j << 2), sA);
                    wj[j]     = __builtin_amdgcn_ds_bpermute(gbase + (j << 2), wbA);
                    sj[8 + j] = __builtin_amdgcn_ds_bpermute(gbase + (j << 2), sB);
                    wj[8 + j] = __builtin_amdgcn_ds_bpermute(gbase + (j << 2), wbB);
                }
                // 16 independent 16B gathers in flight
                int4 r[16];
#pragma unroll
                for (int j = 0; j < 16; ++j)
                    r[j] = *reinterpret_cast<const int4*>(
                        xin + ((size_t)sj[j] << 6) + l8 * 8);
#pragma unroll
                for (int j = 0; j < 16; ++j) {
                    float wf = __int_as_float(wj[j]);
                    acc[0] = fmaf(__int_as_float(r[j].x << 16),        wf, acc[0]);
                    acc[1] = fmaf(__int_as_float(r[j].x & 0xFFFF0000), wf, acc[1]);
                    acc[2] = fmaf(__int_as_float(r[j].y << 16),        wf, acc[2]);
                    acc[3] = fmaf(__int_as_float(r[j].y & 0xFFFF0000), wf, acc[3]);
                    acc[4] = fmaf(__int_as_float(r[j].z << 16),        wf, acc[4]);
                    acc[5] = fmaf(__int_as_float(r[j].z & 0xFFFF0000), wf, acc[5]);
                    acc[6] = fmaf(__int_as_float(r[j].w << 16),        wf, acc[6]);
                    acc[7] = fmaf(__int_as_float(r[j].w & 0xFFFF0000), wf, acc[7]);
                }
            }

            int4 o;
            o.x = (int)f2b(acc[0]) | ((int)f2b(acc[1]) << 16);
            o.y = (int)f2b(acc[2]) | ((int)f2b(acc[3]) << 16);
            o.z = (int)f2b(acc[4]) | ((int)f2b(acc[5]) << 16);
            o.w = (int)f2b(acc[6]) | ((int)f2b(acc[7]) << 16);
            *reinterpret_cast<int4*>(&aggS[wave][half * 8 + grp][l8 * 8]) = o;
        }
        // rows are wave-local: no block barrier needed.

        // ---- GEMM phase: 16-row MFMA tile for this group's nodes
        bf16x8 a0 = *reinterpret_cast<const bf16x8*>(&aggS[wave][l15][lhi * 8]);
        bf16x8 a1 = *reinterpret_cast<const bf16x8*>(&aggS[wave][l15][32 + lhi * 8]);
        const unsigned short* xp = xin + (size_t)min(wbase + l15, n - 1) * GCN_F + lhi * 8;
        bf16x8 x0 = *reinterpret_cast<const bf16x8*>(xp);
        bf16x8 x1 = *reinterpret_cast<const bf16x8*>(xp + 32);

#pragma unroll
        for (int ct = 0; ct < 4; ++ct) {
            f32x4 acc = {0.f, 0.f, 0.f, 0.f};
            acc = __builtin_amdgcn_mfma_f32_16x16x32_bf16(a0, B[0][0][ct], acc, 0, 0, 0);
            acc = __builtin_amdgcn_mfma_f32_16x16x32_bf16(a1, B[0][1][ct], acc, 0, 0, 0);
            acc = __builtin_amdgcn_mfma_f32_16x16x32_bf16(x0, B[1][0][ct], acc, 0, 0, 0);
            acc = __builtin_amdgcn_mfma_f32_16x16x32_bf16(x1, B[1][1][ct], acc, 0, 0, 0);
            int col = ct * 16 + l15;
#pragma unroll
            for (int r = 0; r < 4; ++r) {
                int orow = wbase + lhi * 4 + r;
                if (orow < n) {
                    float v = fmaxf(acc[r] + bias[ct], 0.f);
                    out[(size_t)orow * GCN_F + col] = f2b(v);
                }
            }
        }
    }
}

// ------------------------------------------------- mean pool + linear head
__global__ __launch_bounds__(256) void pool_kernel(
    const unsigned short* __restrict__ h, const int* __restrict__ batch,
    const float* __restrict__ Wl, const float* __restrict__ bl,
    float* __restrict__ out, int n)
{
    int g    = blockIdx.x;
    int tid  = threadIdx.x;
    int lane = tid & 63;
    int wave = tid >> 6;

    int i0, i1;
    {
        int lo = 0, hi = n;
        while (lo < hi) { int mid = (lo + hi) >> 1; if (batch[mid] < g) lo = mid + 1; else hi = mid; }
        i0 = lo;
        lo = i0; hi = n;
        while (lo < hi) { int mid = (lo + hi) >> 1; if (batch[mid] < g + 1) lo = mid + 1; else hi = mid; }
        i1 = lo;
    }

    float s = 0.f;
    for (int i = i0 + wave; i < i1; i += 4) s += b2f(h[(size_t)i * GCN_F + lane]);

    __shared__ float sp[4][GCN_F];
    sp[wave][lane] = s;
    __syncthreads();
    if (wave == 0) {
        float tot = sp[0][lane] + sp[1][lane] + sp[2][lane] + sp[3][lane];
        float cntf = (float)(i1 - i0);
        sp[0][lane] = tot / fmaxf(cntf, 1.f);
    }
    __syncthreads();
    if (tid < GCN_C) {
        float o = bl[tid];
#pragma unroll
        for (int j = 0; j < GCN_F; ++j) o += sp[0][j] * Wl[j * GCN_C + tid];
        out[g * GCN_C + tid] = o;
    }
}

// --------------------------------------------------------------------------
extern "C" void kernel_launch(void* const* d_in, const int* in_sizes, int n_in,
                              void* d_out, int out_size, void* d_ws, size_t ws_size,
                              hipStream_t stream) {
    const float* x     = (const float*)d_in[0];
    const int*   ei    = (const int*)d_in[1];
    const float* ew    = (const float*)d_in[2];
    const int*   batch = (const int*)d_in[3];
    const float* W1r   = (const float*)d_in[4];
    const float* W1s   = (const float*)d_in[5];
    const float* b1    = (const float*)d_in[6];
    const float* W2r   = (const float*)d_in[7];
    const float* W2s   = (const float*)d_in[8];
    const float* b2    = (const float*)d_in[9];
    const float* W3r   = (const float*)d_in[10];
    const float* W3s   = (const float*)d_in[11];
    const float* b3    = (const float*)d_in[12];
    const float* Wl    = (const float*)d_in[13];
    const float* bl    = (const float*)d_in[14];
    float* out = (float*)d_out;

    const int N = in_sizes[0] / GCN_F;   // 100000
    const int E = in_sizes[2];           // 1000000
    const int G = out_size / GCN_C;      // 256
    const int NCB = (N + CB_NODES - 1) / CB_NODES;  // 196 coarse buckets
    const int NGROUPS = (N + 15) / 16;   // 6250

    const int* src = ei;
    const int* dst = ei + E;

    // workspace layout (16B aligned)
    char* ws = (char*)d_ws;
    size_t off = 0;
    size_t csz = ((size_t)NCB * 4 + 15) & ~(size_t)15;
    int* gcursor = (int*)(ws + off);  off += csz;
    int* bend    = (int*)(ws + off);  off += csz;
    int* offsets = (int*)(ws + off);  off += ((size_t)(N + 1) * 4 + 15) & ~(size_t)15;
    int2* ebufA  = (int2*)(ws + off); off += (size_t)NCB * CAP * 8;   // 11.2 MB
    int2* ebufS  = (int2*)(ws + off); off += (size_t)NCB * CAP * 8;   // 11.2 MB
    unsigned short* buf0 = (unsigned short*)(ws + off); off += (size_t)N * GCN_F * 2;
    unsigned short* buf1 = (unsigned short*)(ws + off); off += (size_t)N * GCN_F * 2;

    int sblocks = (E + SC_CHUNK - 1) / SC_CHUNK;
    int zcount  = (int)(csz / 4);   // gcursor only

    cvtz_kernel<<<1024, 256, 0, stream>>>(x, buf0, N * GCN_F / 4, gcursor, zcount);
    scatterC_kernel<<<sblocks, 256, 0, stream>>>(src, dst, ew, gcursor, ebufA, E, NCB);
    sortCB_kernel<<<NCB, 256, 0, stream>>>(ebufA, gcursor, ebufS, offsets, bend, N, E);

    const int LBLK = 512;   // 2 blocks/CU, all co-resident, one round
    // layer 1: buf0 -> buf1 ; layer 2: buf1 -> buf0 ; layer 3: buf0 -> buf1
    layer_kernel<<<LBLK, 512, 0, stream>>>(buf0, offsets, bend, ebufS, W1r, W1s, b1,
                                           buf1, NGROUPS, N);
    layer_kernel<<<LBLK, 512, 0, stream>>>(buf1, offsets, bend, ebufS, W2r, W2s, b2,
                                           buf0, NGROUPS, N);
    layer_kernel<<<LBLK, 512, 0, stream>>>(buf0, offsets, bend, ebufS, W3r, W3s, b3,
                                           buf1, NGROUPS, N);

    pool_kernel<<<G, 256, 0, stream>>>(buf1, batch, Wl, bl, out, N);
}

// Round 20
// 210.142 us; speedup vs baseline: 1.5233x; 1.4590x over previous
//
#include <hip/hip_runtime.h>

// GCNe: 3-layer edge-weighted GCN + mean pool + linear head.
// N=100000, E=1000000, F=H=64, G=256, C=10.
//
// R20 = R19 without the launch_bounds min-waves clamp: R19's (512,4) capped
// VGPR at 64 and spilled r[16] to scratch (WRITE_SIZE 12.5->91 MB, FETCH
// 100->160 MB, layer 48->80us). Plain (512) lets VGPR ~116 (<128 keeps
// 4 waves/SIMD = 2 blocks/CU) -> clean test of 16-deep gather chunks.

#define GCN_F 64
#define GCN_C 10
#define CB_SHIFT 9
#define CB_NODES 512          // nodes per coarse bucket
#define NCB_MAX 200           // >= ceil(N/512)=196
#define CAP 7168              // bucket slice stride (mean 5102, +29 sigma)
#define SC_CHUNK 2048         // edges per scatter block

typedef __attribute__((ext_vector_type(8))) short bf16x8;
typedef __attribute__((ext_vector_type(4))) float f32x4;

__device__ __forceinline__ unsigned short f2b(float v) {
    union { float f; unsigned int u; } c; c.f = v;
    unsigned int u = c.u;
    return (unsigned short)((u + 0x7FFFu + ((u >> 16) & 1u)) >> 16);  // RNE
}
__device__ __forceinline__ float b2f(unsigned short u) {
    union { unsigned int u; float f; } c; c.u = ((unsigned int)u) << 16; return c.f;
}

// --------------------- fp32 -> bf16 convert + zero cursors
__global__ __launch_bounds__(256) void cvtz_kernel(const float* __restrict__ in,
                                                   unsigned short* __restrict__ out,
                                                   int n4, int* __restrict__ zp, int zn) {
    int gid = blockIdx.x * 256 + threadIdx.x;
    if (gid < zn) zp[gid] = 0;
    int stride = gridDim.x * 256;
    for (int i = gid; i < n4; i += stride) {
        float4 v = reinterpret_cast<const float4*>(in)[i];
        ushort4 o;
        o.x = f2b(v.x); o.y = f2b(v.y); o.z = f2b(v.z); o.w = f2b(v.w);
        reinterpret_cast<ushort4*>(out)[i] = o;
    }
}

// ------------- scatter: block-local counting sort + chunk-reserved run writes
// into fixed-stride bucket slices [bk*CAP, ...). rec.x = src | (dst&511)<<17.
__global__ __launch_bounds__(256) void scatterC_kernel(
    const int* __restrict__ src, const int* __restrict__ dst,
    const float* __restrict__ ew,
    int* __restrict__ gcursor, int2* __restrict__ ebufA, int E, int NCB) {
    __shared__ int2 recS[SC_CHUNK];     // 16 KB
    __shared__ int gdest[SC_CHUNK];     // 8 KB
    __shared__ int hist[NCB_MAX];
    __shared__ int lstart[NCB_MAX];
    __shared__ int gbase[NCB_MAX];
    __shared__ int cur[NCB_MAX];
    __shared__ int sb[256];

    int tid = threadIdx.x;
    int base = blockIdx.x * SC_CHUNK;
    int m = min(SC_CHUNK, E - base);

    for (int i = tid; i < NCB; i += 256) hist[i] = 0;
    __syncthreads();

    int2 rec[8];
    int bk[8];
#pragma unroll
    for (int k = 0; k < 8; ++k) {
        int e = base + k * 256 + tid;
        if (e < E) {
            int d = dst[e];
            bk[k] = d >> CB_SHIFT;
            rec[k] = make_int2(src[e] | ((d & (CB_NODES - 1)) << 17),
                               __float_as_int(ew[e]));
            atomicAdd(&hist[bk[k]], 1);
        } else bk[k] = -1;
    }
    __syncthreads();

    // block-wide exclusive scan of hist[0..NCB)
    int v = (tid < NCB) ? hist[tid] : 0;
    sb[tid] = v;
    __syncthreads();
    for (int o = 1; o < 256; o <<= 1) {
        int t = (tid >= o) ? sb[tid - o] : 0;
        __syncthreads();
        sb[tid] += t;
        __syncthreads();
    }
    if (tid < NCB) {
        int excl = sb[tid] - v;
        lstart[tid] = excl;
        cur[tid] = excl;
        gbase[tid] = (v > 0) ? atomicAdd(&gcursor[tid], v) : 0;  // reserve run
    }
    __syncthreads();

    // place records into LDS sorted by bucket; record global destination
#pragma unroll
    for (int k = 0; k < 8; ++k) {
        if (bk[k] >= 0) {
            int p = atomicAdd(&cur[bk[k]], 1);
            recS[p] = rec[k];
            gdest[p] = bk[k] * CAP + gbase[bk[k]] + (p - lstart[bk[k]]);
        }
    }
    __syncthreads();

    // coalesced staged write (consecutive i within a run -> consecutive dest)
    for (int i = tid; i < m; i += 256) ebufA[gdest[i]] = recS[i];
}

// -------------- per-bucket LDS counting sort -> sorted edges + node offsets
// Also records bend[cb] = slice-local end, for bucket-boundary nodes.
__global__ __launch_bounds__(256) void sortCB_kernel(
    const int2* __restrict__ ebufA, const int* __restrict__ gcursor,
    int2* __restrict__ ebufS, int* __restrict__ offsets, int* __restrict__ bend,
    int N, int E) {
    __shared__ int2 rec[CAP];                 // 56 KB
    __shared__ int cnt[CB_NODES];
    __shared__ int cur[CB_NODES];
    __shared__ int sbuf[256];
    int cb = blockIdx.x, tid = threadIdx.x;
    int e0 = cb * CAP;
    int m = min(gcursor[cb], CAP);
    if (tid == 0) bend[cb] = e0 + m;

    for (int i = tid; i < m; i += 256) rec[i] = ebufA[e0 + i];
    for (int i = tid; i < CB_NODES; i += 256) cnt[i] = 0;
    __syncthreads();
    for (int i = tid; i < m; i += 256)
        atomicAdd(&cnt[(unsigned)rec[i].x >> 17], 1);
    __syncthreads();

    // exclusive scan over 512 counts (thread owns 2)
    int c0 = cnt[2 * tid], c1 = cnt[2 * tid + 1];
    int part = c0 + c1;
    sbuf[tid] = part;
    __syncthreads();
    for (int off = 1; off < 256; off <<= 1) {
        int t = (tid >= off) ? sbuf[tid - off] : 0;
        __syncthreads();
        sbuf[tid] += t;
        __syncthreads();
    }
    int excl = sbuf[tid] - part;
    int pre0 = excl, pre1 = excl + c0;
    cur[2 * tid] = pre0;
    cur[2 * tid + 1] = pre1;
    int g0 = cb * CB_NODES + 2 * tid;
    if (g0 <= N)     offsets[g0]     = e0 + pre0;
    if (g0 + 1 <= N) offsets[g0 + 1] = e0 + pre1;
    __syncthreads();

    for (int i = tid; i < m; i += 256) {
        int d9 = (unsigned)rec[i].x >> 17;
        int pos = atomicAdd(&cur[d9], 1);
        ebufS[e0 + pos] = make_int2(rec[i].x & 0x1FFFF, rec[i].y);
    }
}

// ---------------- fused layer: 512-thr blocks, 8 waves; wave wid statically
// handles groups wid, wid+nw, ... Per group: spmm (2x 8-node halves, 16-deep
// int4 gather chunks, ds_bpermute broadcast) -> padded LDS rows -> wave-local
// MFMA tile: h = relu(agg@Wr + x@Ws + b).
__global__ __launch_bounds__(512) void layer_kernel(
    const unsigned short* __restrict__ xin, const int* __restrict__ offsets,
    const int* __restrict__ bend, const int2* __restrict__ ebufS,
    const float* __restrict__ Wr, const float* __restrict__ Ws,
    const float* __restrict__ b, unsigned short* __restrict__ out,
    int ngroups, int n)
{
    __shared__ __align__(16) unsigned short bfrag[2][2][4][64][8];  // 16 KB
    __shared__ __align__(16) unsigned short aggS[8][16][72];        // 18.4 KB
    int tid = threadIdx.x, lane = tid & 63, wave = tid >> 6;

    // build B fragments: [op][ks][ct][lane][j]
    for (int i = tid; i < 8192; i += 512) {
        int op = i >> 12;
        int ks = (i >> 11) & 1;
        int ct = (i >> 9) & 3;
        int l  = (i >> 3) & 63;
        int j  = i & 7;
        int k   = ks * 32 + (l >> 4) * 8 + j;
        int col = ct * 16 + (l & 15);
        const float* W = op ? Ws : Wr;
        ((unsigned short*)bfrag)[i] = f2b(W[k * GCN_F + col]);
    }
    __syncthreads();

    int l8 = lane & 7;
    int grp = lane >> 3;
    int gbase = (lane & 56) << 2;           // byte addr of group's lane 0
    int l15 = lane & 15, lhi = lane >> 4;

    bf16x8 B[2][2][4];
#pragma unroll
    for (int op = 0; op < 2; ++op)
#pragma unroll
        for (int ks = 0; ks < 2; ++ks)
#pragma unroll
            for (int ct = 0; ct < 4; ++ct)
                B[op][ks][ct] = *reinterpret_cast<const bf16x8*>(&bfrag[op][ks][ct][lane][0]);

    float bias[4];
#pragma unroll
    for (int ct = 0; ct < 4; ++ct) bias[ct] = b[ct * 16 + l15];

    int wid = blockIdx.x * 8 + wave;
    int nw  = gridDim.x * 8;
    for (int gsel = wid; gsel < ngroups; gsel += nw) {
        int wbase = gsel * 16;

        // ---- spmm phase: this group's 16 nodes, two 8-node halves
#pragma unroll
        for (int half = 0; half < 2; ++half) {
            int node = wbase + half * 8 + grp;
            bool nv = node < n;
            int p0 = 0, p1 = 0;
            if (nv) {
                p0 = offsets[node];
                // bucket's last node ends at the slice end, not the next
                // bucket's slice start (the gap is uninitialized!)
                p1 = ((node & (CB_NODES - 1)) == CB_NODES - 1)
                         ? bend[node >> CB_SHIFT] : offsets[node + 1];
            }
            float acc[8] = {0.f, 0.f, 0.f, 0.f, 0.f, 0.f, 0.f, 0.f};

            // 16-deep chunks: lanes hold edges c*16+l8 and c*16+8+l8
            for (int c = 0; p0 + c * 16 < p1 || c == 0; ++c) {
                if (!__any(p0 + c * 16 + l8 < p1)) break;
                int idxA = p0 + c * 16 + l8;
                int idxB = idxA + 8;
                bool vA = idxA < p1;
                bool vB = idxB < p1;
                int2 erA = ebufS[vA ? idxA : 0];
                int2 erB = ebufS[vB ? idxB : 0];
                int sA = vA ? erA.x : 0, wbA = vA ? erA.y : 0;
                int sB = vB ? erB.x : 0, wbB = vB ? erB.y : 0;

                int sj[16], wj[16];
#pragma unroll
                for (int j = 0; j < 8; ++j) {
                    sj[j]     = __builtin_amdgcn_ds_bpermute(gbase + (j << 2), sA);
                    wj[j]     = __builtin_amdgcn_ds_bpermute(gbase + (j << 2), wbA);
                    sj[8 + j] = __builtin_amdgcn_ds_bpermute(gbase + (j << 2), sB);
                    wj[8 + j] = __builtin_amdgcn_ds_bpermute(gbase + (j << 2), wbB);
                }
                // 16 independent 16B gathers in flight
                int4 r[16];
#pragma unroll
                for (int j = 0; j < 16; ++j)
                    r[j] = *reinterpret_cast<const int4*>(
                        xin + ((size_t)sj[j] << 6) + l8 * 8);
#pragma unroll
                for (int j = 0; j < 16; ++j) {
                    float wf = __int_as_float(wj[j]);
                    acc[0] = fmaf(__int_as_float(r[j].x << 16),        wf, acc[0]);
                    acc[1] = fmaf(__int_as_float(r[j].x & 0xFFFF0000), wf, acc[1]);
                    acc[2] = fmaf(__int_as_float(r[j].y << 16),        wf, acc[2]);
                    acc[3] = fmaf(__int_as_float(r[j].y & 0xFFFF0000), wf, acc[3]);
                    acc[4] = fmaf(__int_as_float(r[j].z << 16),        wf, acc[4]);
                    acc[5] = fmaf(__int_as_float(r[j].z & 0xFFFF0000), wf, acc[5]);
                    acc[6] = fmaf(__int_as_float(r[j].w << 16),        wf, acc[6]);
                    acc[7] = fmaf(__int_as_float(r[j].w & 0xFFFF0000), wf, acc[7]);
                }
            }

            int4 o;
            o.x = (int)f2b(acc[0]) | ((int)f2b(acc[1]) << 16);
            o.y = (int)f2b(acc[2]) | ((int)f2b(acc[3]) << 16);
            o.z = (int)f2b(acc[4]) | ((int)f2b(acc[5]) << 16);
            o.w = (int)f2b(acc[6]) | ((int)f2b(acc[7]) << 16);
            *reinterpret_cast<int4*>(&aggS[wave][half * 8 + grp][l8 * 8]) = o;
        }
        // rows are wave-local: no block barrier needed.

        // ---- GEMM phase: 16-row MFMA tile for this group's nodes
        bf16x8 a0 = *reinterpret_cast<const bf16x8*>(&aggS[wave][l15][lhi * 8]);
        bf16x8 a1 = *reinterpret_cast<const bf16x8*>(&aggS[wave][l15][32 + lhi * 8]);
        const unsigned short* xp = xin + (size_t)min(wbase + l15, n - 1) * GCN_F + lhi * 8;
        bf16x8 x0 = *reinterpret_cast<const bf16x8*>(xp);
        bf16x8 x1 = *reinterpret_cast<const bf16x8*>(xp + 32);

#pragma unroll
        for (int ct = 0; ct < 4; ++ct) {
            f32x4 acc = {0.f, 0.f, 0.f, 0.f};
            acc = __builtin_amdgcn_mfma_f32_16x16x32_bf16(a0, B[0][0][ct], acc, 0, 0, 0);
            acc = __builtin_amdgcn_mfma_f32_16x16x32_bf16(a1, B[0][1][ct], acc, 0, 0, 0);
            acc = __builtin_amdgcn_mfma_f32_16x16x32_bf16(x0, B[1][0][ct], acc, 0, 0, 0);
            acc = __builtin_amdgcn_mfma_f32_16x16x32_bf16(x1, B[1][1][ct], acc, 0, 0, 0);
            int col = ct * 16 + l15;
#pragma unroll
            for (int r = 0; r < 4; ++r) {
                int orow = wbase + lhi * 4 + r;
                if (orow < n) {
                    float v = fmaxf(acc[r] + bias[ct], 0.f);
                    out[(size_t)orow * GCN_F + col] = f2b(v);
                }
            }
        }
    }
}

// ------------------------------------------------- mean pool + linear head
__global__ __launch_bounds__(256) void pool_kernel(
    const unsigned short* __restrict__ h, const int* __restrict__ batch,
    const float* __restrict__ Wl, const float* __restrict__ bl,
    float* __restrict__ out, int n)
{
    int g    = blockIdx.x;
    int tid  = threadIdx.x;
    int lane = tid & 63;
    int wave = tid >> 6;

    int i0, i1;
    {
        int lo = 0, hi = n;
        while (lo < hi) { int mid = (lo + hi) >> 1; if (batch[mid] < g) lo = mid + 1; else hi = mid; }
        i0 = lo;
        lo = i0; hi = n;
        while (lo < hi) { int mid = (lo + hi) >> 1; if (batch[mid] < g + 1) lo = mid + 1; else hi = mid; }
        i1 = lo;
    }

    float s = 0.f;
    for (int i = i0 + wave; i < i1; i += 4) s += b2f(h[(size_t)i * GCN_F + lane]);

    __shared__ float sp[4][GCN_F];
    sp[wave][lane] = s;
    __syncthreads();
    if (wave == 0) {
        float tot = sp[0][lane] + sp[1][lane] + sp[2][lane] + sp[3][lane];
        float cntf = (float)(i1 - i0);
        sp[0][lane] = tot / fmaxf(cntf, 1.f);
    }
    __syncthreads();
    if (tid < GCN_C) {
        float o = bl[tid];
#pragma unroll
        for (int j = 0; j < GCN_F; ++j) o += sp[0][j] * Wl[j * GCN_C + tid];
        out[g * GCN_C + tid] = o;
    }
}

// --------------------------------------------------------------------------
extern "C" void kernel_launch(void* const* d_in, const int* in_sizes, int n_in,
                              void* d_out, int out_size, void* d_ws, size_t ws_size,
                              hipStream_t stream) {
    const float* x     = (const float*)d_in[0];
    const int*   ei    = (const int*)d_in[1];
    const float* ew    = (const float*)d_in[2];
    const int*   batch = (const int*)d_in[3];
    const float* W1r   = (const float*)d_in[4];
    const float* W1s   = (const float*)d_in[5];
    const float* b1    = (const float*)d_in[6];
    const float* W2r   = (const float*)d_in[7];
    const float* W2s   = (const float*)d_in[8];
    const float* b2    = (const float*)d_in[9];
    const float* W3r   = (const float*)d_in[10];
    const float* W3s   = (const float*)d_in[11];
    const float* b3    = (const float*)d_in[12];
    const float* Wl    = (const float*)d_in[13];
    const float* bl    = (const float*)d_in[14];
    float* out = (float*)d_out;

    const int N = in_sizes[0] / GCN_F;   // 100000
    const int E = in_sizes[2];           // 1000000
    const int G = out_size / GCN_C;      // 256
    const int NCB = (N + CB_NODES - 1) / CB_NODES;  // 196 coarse buckets
    const int NGROUPS = (N + 15) / 16;   // 6250

    const int* src = ei;
    const int* dst = ei + E;

    // workspace layout (16B aligned)
    char* ws = (char*)d_ws;
    size_t off = 0;
    size_t csz = ((size_t)NCB * 4 + 15) & ~(size_t)15;
    int* gcursor = (int*)(ws + off);  off += csz;
    int* bend    = (int*)(ws + off);  off += csz;
    int* offsets = (int*)(ws + off);  off += ((size_t)(N + 1) * 4 + 15) & ~(size_t)15;
    int2* ebufA  = (int2*)(ws + off); off += (size_t)NCB * CAP * 8;   // 11.2 MB
    int2* ebufS  = (int2*)(ws + off); off += (size_t)NCB * CAP * 8;   // 11.2 MB
    unsigned short* buf0 = (unsigned short*)(ws + off); off += (size_t)N * GCN_F * 2;
    unsigned short* buf1 = (unsigned short*)(ws + off); off += (size_t)N * GCN_F * 2;

    int sblocks = (E + SC_CHUNK - 1) / SC_CHUNK;
    int zcount  = (int)(csz / 4);   // gcursor only

    cvtz_kernel<<<1024, 256, 0, stream>>>(x, buf0, N * GCN_F / 4, gcursor, zcount);
    scatterC_kernel<<<sblocks, 256, 0, stream>>>(src, dst, ew, gcursor, ebufA, E, NCB);
    sortCB_kernel<<<NCB, 256, 0, stream>>>(ebufA, gcursor, ebufS, offsets, bend, N, E);

    const int LBLK = 512;   // 2 blocks/CU, all co-resident, one round
    // layer 1: buf0 -> buf1 ; layer 2: buf1 -> buf0 ; layer 3: buf0 -> buf1
    layer_kernel<<<LBLK, 512, 0, stream>>>(buf0, offsets, bend, ebufS, W1r, W1s, b1,
                                           buf1, NGROUPS, N);
    layer_kernel<<<LBLK, 512, 0, stream>>>(buf1, offsets, bend, ebufS, W2r, W2s, b2,
                                           buf0, NGROUPS, N);
    layer_kernel<<<LBLK, 512, 0, stream>>>(buf0, offsets, bend, ebufS, W3r, W3s, b3,
                                           buf1, NGROUPS, N);

    pool_kernel<<<G, 256, 0, stream>>>(buf1, batch, Wl, bl, out, N);
}